// Round 7
// baseline (398.590 us; speedup 1.0000x reference)
//
#include <hip/hip_runtime.h>

// Problem constants
static constexpr int Bb = 8, Nn = 16384, Cc = 256, KO = 48, KK = 16;
#define EPSBN 1e-5f

typedef short bf16x8 __attribute__((ext_vector_type(8)));
typedef float f32x4 __attribute__((ext_vector_type(4)));
typedef unsigned short u16x4 __attribute__((ext_vector_type(4)));

__device__ __forceinline__ unsigned short f2bf(float f) {
  unsigned u = __builtin_bit_cast(unsigned, f);
  u += 0x7FFFu + ((u >> 16) & 1u);   // round-to-nearest-even
  return (unsigned short)(u >> 16);
}

// Blocked LDS layout, 64-pt x 256-ch bf16 tile:
// element (p, c) at ushort index (c/8)*512 + p*8 + (c%8).
#define LADDR(p, c) ((((c) >> 3) << 9) + ((p) << 3) + ((c) & 7))

// ---------------------------------------------------------------------------
// prep: weights fp32 -> bf16, MFMA-fragment-major swizzle; BN scale/shift;
// zeroes wsum (folded memset).
// ---------------------------------------------------------------------------
__global__ void prep_k(const float* __restrict__ W1, const float* __restrict__ W2,
                       const float* __restrict__ W3, const float* __restrict__ Wo,
                       const float* __restrict__ g1, const float* __restrict__ bb1,
                       const float* __restrict__ m1, const float* __restrict__ v1,
                       const float* __restrict__ g2, const float* __restrict__ bb2,
                       const float* __restrict__ m2, const float* __restrict__ v2,
                       const float* __restrict__ g3, const float* __restrict__ bb3,
                       const float* __restrict__ m3, const float* __restrict__ v3,
                       unsigned short* __restrict__ W1b, unsigned short* __restrict__ W2b,
                       unsigned short* __restrict__ W3b, unsigned short* __restrict__ Wob,
                       float* __restrict__ st1, float* __restrict__ st2,
                       float* __restrict__ st3, float* __restrict__ wsum) {
  int gid = blockIdx.x * 256 + threadIdx.x;
  if (gid < 65536) {
    int r = gid >> 8, k = gid & 255;
    int dst = (((r >> 4) * 8 + (k >> 5)) << 9) + (((r & 15) | (((k >> 3) & 3) << 4)) << 3) + (k & 7);
    W1b[dst] = f2bf(W1[gid]);
  } else if (gid < 131072) {
    int g = gid - 65536;
    int r = g >> 8, k = g & 255;
    int dst = (((r >> 4) * 8 + (k >> 5)) << 9) + (((r & 15) | (((k >> 3) & 3) << 4)) << 3) + (k & 7);
    W2b[dst] = f2bf(W2[g]);
  } else if (gid < 262144) {
    int g = gid - 131072;
    int r = g >> 8, k = g & 255;           // r in [0,512)
    int h = r >> 8, rr = r & 255;
    int dst = h * 65536 + ((((rr >> 4) * 8 + (k >> 5))) << 9) +
              (((rr & 15) | (((k >> 3) & 3) << 4)) << 3) + (k & 7);
    W3b[dst] = f2bf(W3[g]);
  } else if (gid < 286720) {
    int g = gid - 262144;
    int r = g >> 9, k = g & 511;           // Wo is 48 x 512
    int dst = (((r >> 4) * 16 + (k >> 5)) << 9) + (((r & 15) | (((k >> 3) & 3) << 4)) << 3) + (k & 7);
    Wob[dst] = f2bf(Wo[g]);
  }
  if (gid < 256) {
    float s = g1[gid] * rsqrtf(v1[gid] + EPSBN);
    st1[2 * gid] = s; st1[2 * gid + 1] = bb1[gid] - m1[gid] * s;
  } else if (gid < 512) {
    int i = gid - 256;
    float s = g2[i] * rsqrtf(v2[i] + EPSBN);
    st2[2 * i] = s; st2[2 * i + 1] = bb2[i] - m2[i] * s;
  } else if (gid < 1024) {
    int i = gid - 512;
    float s = g3[i] * rsqrtf(v3[i] + EPSBN);
    st3[2 * i] = s; st3[2 * i + 1] = bb3[i] - m3[i] * s;
  } else if (gid < 1024 + Bb * KK) {
    wsum[gid - 1024] = 0.f;
  }
}

// ---------------------------------------------------------------------------
// backbone: 256 threads (4 waves), 64 points/block, 2 blocks/CU. (round-6 WIN,
// unchanged) Quarter-K software pipeline, sched_barrier pins the load ring.
// ---------------------------------------------------------------------------
__device__ __forceinline__ void gemm64(const unsigned short* __restrict__ src,
                                       unsigned short* __restrict__ dst,
                                       const unsigned short* __restrict__ Wsw,
                                       const float* __restrict__ st, int tid) {
  const int lane = tid & 63;
  const int cg = tid >> 6;        // wave = ch-group (64 ch)
  const int ln15 = lane & 15;
  const int q = lane >> 4;
  f32x4 acc[4][4] = {};
  const unsigned short* wb = Wsw + ((cg * 32) << 9) + lane * 8;

  bf16x8 A[2][8], Bf[2][8];
#pragma unroll
  for (int ct = 0; ct < 4; ++ct)
#pragma unroll
    for (int k2 = 0; k2 < 2; ++k2)
      A[0][ct * 2 + k2] = *reinterpret_cast<const bf16x8*>(wb + ((ct * 8 + k2) << 9));
#pragma unroll
  for (int pt = 0; pt < 4; ++pt)
#pragma unroll
    for (int k2 = 0; k2 < 2; ++k2)
      Bf[0][pt * 2 + k2] = *reinterpret_cast<const bf16x8*>(
          &src[((k2 * 4 + q) << 9) + ((pt * 16 + ln15) << 3)]);

#pragma unroll
  for (int h = 0; h < 4; ++h) {
    const int cur = h & 1, nxt = cur ^ 1;
    if (h < 3) {
      const int kb0 = (h + 1) * 2;
#pragma unroll
      for (int ct = 0; ct < 4; ++ct)
#pragma unroll
        for (int k2 = 0; k2 < 2; ++k2)
          A[nxt][ct * 2 + k2] = *reinterpret_cast<const bf16x8*>(wb + ((ct * 8 + kb0 + k2) << 9));
#pragma unroll
      for (int pt = 0; pt < 4; ++pt)
#pragma unroll
        for (int k2 = 0; k2 < 2; ++k2)
          Bf[nxt][pt * 2 + k2] = *reinterpret_cast<const bf16x8*>(
              &src[(((kb0 + k2) * 4 + q) << 9) + ((pt * 16 + ln15) << 3)]);
    }
    __builtin_amdgcn_sched_barrier(0);   // loads above may not sink below
#pragma unroll
    for (int k2 = 0; k2 < 2; ++k2)
#pragma unroll
      for (int ct = 0; ct < 4; ++ct)
#pragma unroll
        for (int pt = 0; pt < 4; ++pt)
          acc[ct][pt] = __builtin_amdgcn_mfma_f32_16x16x32_bf16(
              A[cur][ct * 2 + k2], Bf[cur][pt * 2 + k2], acc[ct][pt], 0, 0, 0);
  }

  // epilogue: BN + ReLU, fp32 -> bf16, blocked LDS write
#pragma unroll
  for (int ct = 0; ct < 4; ++ct) {
    const int chl = cg * 64 + ct * 16 + q * 4;
    float s0[4], t0[4];
#pragma unroll
    for (int r = 0; r < 4; ++r) {
      s0[r] = st[2 * (chl + r)];
      t0[r] = st[2 * (chl + r) + 1];
    }
#pragma unroll
    for (int pt = 0; pt < 4; ++pt) {
      const int p = pt * 16 + ln15;
      u16x4 hv;
#pragma unroll
      for (int r = 0; r < 4; ++r) {
        float v = fmaxf(acc[ct][pt][r] * s0[r] + t0[r], 0.f);
        hv[r] = f2bf(v);
      }
      *reinterpret_cast<u16x4*>(&dst[LADDR(p, chl)]) = hv;
    }
  }
}

// Wo partial: wave owns 16 points (4 waves x 16 = 64), all 48 output rows.
__device__ __forceinline__ void wo64(const unsigned short* __restrict__ src,
                                     const unsigned short* __restrict__ Wosw,
                                     int h, f32x4* accO, int tid) {
  const int lane = tid & 63;
  const int wave = tid >> 6;
  const int ln15 = lane & 15;
  const int q = lane >> 4;
#pragma unroll
  for (int kb = 0; kb < 8; ++kb) {
    bf16x8 bfr = *reinterpret_cast<const bf16x8*>(
        &src[((kb * 4 + q) << 9) + ((wave * 16 + ln15) << 3)]);
#pragma unroll
    for (int ot = 0; ot < 3; ++ot) {
      bf16x8 afr = *reinterpret_cast<const bf16x8*>(&Wosw[((ot * 16 + 8 * h + kb) << 9) + lane * 8]);
      accO[ot] = __builtin_amdgcn_mfma_f32_16x16x32_bf16(afr, bfr, accO[ot], 0, 0, 0);
    }
  }
}

__global__ __launch_bounds__(256, 2) void backbone_k(
    const float* __restrict__ ff, const float* __restrict__ xyz,
    const unsigned short* __restrict__ W1b, const unsigned short* __restrict__ W2b,
    const unsigned short* __restrict__ W3b, const unsigned short* __restrict__ Wob,
    const float* __restrict__ st1, const float* __restrict__ st2,
    const float* __restrict__ st3, const float* __restrict__ bo,
    float* __restrict__ voted_t, float* __restrict__ block_part) {
  __shared__ unsigned short bufA[64 * 256];   // 32 KB
  __shared__ unsigned short bufB[64 * 256];   // 32 KB
  __shared__ float sh_part[4][KO];
  const int tid = threadIdx.x;
  const int b = blockIdx.x >> 8;
  const int n0 = (blockIdx.x & 255) * 64;
  const int lane = tid & 63;
  const int wave = tid >> 6;

  // stage ff tile -> bufA (bf16, blocked layout)
  {
    const float* src = ff + (size_t)(b * Nn + n0) * Cc;
#pragma unroll
    for (int i = 0; i < 16; ++i) {
      int p = (tid & 15) + 16 * (i & 3);
      int c4 = (tid >> 4) + 16 * (i >> 2);
      const float4 v = *reinterpret_cast<const float4*>(src + p * Cc + c4 * 4);
      u16x4 h;
      h.x = f2bf(v.x); h.y = f2bf(v.y); h.z = f2bf(v.z); h.w = f2bf(v.w);
      *reinterpret_cast<u16x4*>(&bufA[LADDR(p, c4 * 4)]) = h;
    }
  }
  __syncthreads();

  gemm64(bufA, bufB, W1b, st1, tid);
  __syncthreads();
  gemm64(bufB, bufA, W2b, st2, tid);
  __syncthreads();
  gemm64(bufA, bufB, W3b, st3, tid);
  __syncthreads();

  f32x4 accO[3] = {};
  wo64(bufB, Wob, 0, accO, tid);
  __syncthreads();
  gemm64(bufA, bufB, W3b + 65536, st3 + 512, tid);
  __syncthreads();
  wo64(bufB, Wob, 1, accO, tid);

  // epilogue: voted (transposed [b][o][n]) + block partial sums
  const int ln15 = lane & 15;
  const int q = lane >> 4;
  const int p = wave * 16 + ln15;
  const int n = n0 + p;
  const float* xp = xyz + (size_t)(b * Nn + n) * 3;
  float xv[3] = {xp[0], xp[1], xp[2]};
#pragma unroll
  for (int ot = 0; ot < 3; ++ot) {
#pragma unroll
    for (int r = 0; r < 4; ++r) {
      int o = ot * 16 + q * 4 + r;  // o = k*3 + d
      float v = accO[ot][r] + bo[o] + xv[o % 3];
      voted_t[(((size_t)b * KO + o) << 14) + n] = v;
      float s = v;
      s += __shfl_xor(s, 1, 64);
      s += __shfl_xor(s, 2, 64);
      s += __shfl_xor(s, 4, 64);
      s += __shfl_xor(s, 8, 64);
      if (ln15 == 0) sh_part[wave][o] = s;
    }
  }
  __syncthreads();
  if (tid < KO) {
    float t = sh_part[0][tid] + sh_part[1][tid] + sh_part[2][tid] + sh_part[3][tid];
    block_part[blockIdx.x * KO + tid] = t;
  }
}

// ---------------------------------------------------------------------------
// distpool: fused kp-finalize + dist + UNNORMALIZED pooling (normalization is
// linear -> deferred to mlp). No wexp tensor. 512 blocks (256 pts), 2/CU.
// Per block: reduce kp from block_part; e[k]=exp(-dist) -> LDS wt (stride 20);
// wsum block-partials via 16 tiny atomics; pooling: wave owns 64 pts, lane
// owns 4 ch; per-wave partial out via plain coalesced stores.
// ---------------------------------------------------------------------------
__global__ __launch_bounds__(256, 2) void distpool_k(
    const float* __restrict__ block_part, const float* __restrict__ voted_t,
    const float* __restrict__ ff, float* __restrict__ out,
    float* __restrict__ wsum, float* __restrict__ part) {
  __shared__ float kp[KO];
  __shared__ float sh[4][KO];
  __shared__ float red[64];
  __shared__ float wt[256 * 20];   // 20 KB, padded stride
  const int b = blockIdx.x >> 6;
  const int n0 = (blockIdx.x & 63) * 256;
  const int tid = threadIdx.x;

  // kp finalize (redundant per block; 48 KB L2/L3 reads)
  if (tid < 192) {
    int o = tid % KO, c = tid / KO;
    const float* bp = block_part + ((size_t)b * 256 + c * 64) * KO + o;
    float s = 0.f;
#pragma unroll 8
    for (int j = 0; j < 64; ++j) s += bp[j * KO];
    sh[c][o] = s;
  }
  __syncthreads();
  if (tid < KO) {
    float v = (sh[0][tid] + sh[1][tid] + sh[2][tid] + sh[3][tid]) * (1.0f / (float)Nn);
    kp[tid] = v;
    if ((blockIdx.x & 63) == 0) out[b * KO + tid] = v;
  }
  __syncthreads();

  // e[k] = exp(-dist) for this thread's point
  const int n = n0 + tid;
  float e[KK];
#pragma unroll
  for (int k = 0; k < KK; ++k) {
    const float* base = voted_t + (((size_t)b * KO + 3 * k) << 14) + n;
    float dx = base[0] - kp[3 * k];
    float dy = base[1 << 14] - kp[3 * k + 1];
    float dz = base[2 << 14] - kp[3 * k + 2];
    e[k] = __expf(-sqrtf(dx * dx + dy * dy + dz * dz));
    wt[tid * 20 + k] = e[k];
  }
  // wsum partial
  const int wave = tid >> 6;
  const int lane = tid & 63;
#pragma unroll
  for (int k = 0; k < KK; ++k) {
    float s = e[k];
#pragma unroll
    for (int m = 1; m < 64; m <<= 1) s += __shfl_xor(s, m, 64);
    if (lane == 0) red[wave * KK + k] = s;
  }
  __syncthreads();
  if (tid < KK) {
    float s = red[tid] + red[KK + tid] + red[2 * KK + tid] + red[3 * KK + tid];
    atomicAdd(&wsum[b * KK + tid], s);
  }

  // unnormalized pooling: wave owns 64 pts, lane owns 4 channels
  const float* fp = ff + (size_t)(b * Nn + n0 + wave * 64) * Cc + lane * 4;
  f32x4 acc[KK] = {};
  for (int p = 0; p < 64; ++p) {
    f32x4 f = *reinterpret_cast<const f32x4*>(fp + (size_t)p * Cc);
    const float* wr = &wt[(wave * 64 + p) * 20];
    f32x4 w0 = *reinterpret_cast<const f32x4*>(wr);
    f32x4 w1 = *reinterpret_cast<const f32x4*>(wr + 4);
    f32x4 w2 = *reinterpret_cast<const f32x4*>(wr + 8);
    f32x4 w3 = *reinterpret_cast<const f32x4*>(wr + 12);
#pragma unroll
    for (int j = 0; j < 4; ++j) {
      acc[0 + j] += f * w0[j];
      acc[4 + j] += f * w1[j];
      acc[8 + j] += f * w2[j];
      acc[12 + j] += f * w3[j];
    }
  }
  float* dst = part + (((size_t)blockIdx.x * 4 + wave) << 12) + lane * 4;
#pragma unroll
  for (int k = 0; k < KK; ++k)
    *reinterpret_cast<f32x4*>(dst + (k << 8)) = acc[k];
}

// ---------------------------------------------------------------------------
// keypoint MLP: one block per (b,k); reduce 256 pool partials, scale by
// 1/wsum (deferred normalization), then 3 fp32 layers.
// ---------------------------------------------------------------------------
__global__ __launch_bounds__(256) void mlp_k(
    const float* __restrict__ part, const float* __restrict__ wsum,
    const float* __restrict__ Wm1, const float* __restrict__ gm1,
    const float* __restrict__ bm1, const float* __restrict__ mm1,
    const float* __restrict__ vm1,
    const float* __restrict__ Wm2, const float* __restrict__ gm2,
    const float* __restrict__ bm2, const float* __restrict__ mm2,
    const float* __restrict__ vm2,
    const float* __restrict__ Wm3, float* __restrict__ out) {
  __shared__ float xa[256];
  __shared__ float xb[256];
  const int bk = blockIdx.x;
  const int b = bk >> 4;
  const int k = bk & 15;
  const int d = threadIdx.x;
  {
    // partials for batch b: blocks b*64..b*64+63, 4 waves each -> 256 vectors
    const float* pp = part + (((size_t)(b * 64) * 4) << 12) + (k << 8) + d;
    float s = 0.f;
#pragma unroll 4
    for (int j = 0; j < 256; ++j) s += pp[(size_t)j << 12];
    xa[d] = s / wsum[b * KK + k];
  }
  __syncthreads();
  float acc = 0.f;
  {
    const float4* w4 = reinterpret_cast<const float4*>(Wm1 + d * 256);
    const float4* x4 = reinterpret_cast<const float4*>(xa);
    for (int c = 0; c < 64; ++c) {
      float4 w = w4[c], x = x4[c];
      acc += w.x * x.x + w.y * x.y + w.z * x.z + w.w * x.w;
    }
  }
  {
    float s = gm1[d] * rsqrtf(vm1[d] + EPSBN);
    xb[d] = fmaxf(acc * s + (bm1[d] - mm1[d] * s), 0.f);
  }
  __syncthreads();
  acc = 0.f;
  {
    const float4* w4 = reinterpret_cast<const float4*>(Wm2 + d * 256);
    const float4* x4 = reinterpret_cast<const float4*>(xb);
    for (int c = 0; c < 64; ++c) {
      float4 w = w4[c], x = x4[c];
      acc += w.x * x.x + w.y * x.y + w.z * x.z + w.w * x.w;
    }
  }
  {
    float s = gm2[d] * rsqrtf(vm2[d] + EPSBN);
    xa[d] = fmaxf(acc * s + (bm2[d] - mm2[d] * s), 0.f);
  }
  __syncthreads();
  acc = 0.f;
  {
    const float4* w4 = reinterpret_cast<const float4*>(Wm3 + d * 256);
    const float4* x4 = reinterpret_cast<const float4*>(xa);
    for (int c = 0; c < 64; ++c) {
      float4 w = w4[c], x = x4[c];
      acc += w.x * x.x + w.y * x.y + w.z * x.z + w.w * x.w;
    }
  }
  out[384 + bk * 256 + d] = acc;
}

// ---------------------------------------------------------------------------
// launch (4 dispatches)
// ---------------------------------------------------------------------------
extern "C" void kernel_launch(void* const* d_in, const int* in_sizes, int n_in,
                              void* d_out, int out_size, void* d_ws, size_t ws_size,
                              hipStream_t stream) {
  const float* ff  = (const float*)d_in[0];
  const float* xyz = (const float*)d_in[1];
  const float* W1 = (const float*)d_in[2];
  const float* g1 = (const float*)d_in[3];
  const float* b1 = (const float*)d_in[4];
  const float* m1 = (const float*)d_in[5];
  const float* v1 = (const float*)d_in[6];
  const float* W2 = (const float*)d_in[7];
  const float* g2 = (const float*)d_in[8];
  const float* b2 = (const float*)d_in[9];
  const float* m2 = (const float*)d_in[10];
  const float* v2 = (const float*)d_in[11];
  const float* W3 = (const float*)d_in[12];
  const float* g3 = (const float*)d_in[13];
  const float* b3 = (const float*)d_in[14];
  const float* m3 = (const float*)d_in[15];
  const float* v3 = (const float*)d_in[16];
  const float* Wo = (const float*)d_in[17];
  const float* bo = (const float*)d_in[18];
  const float* Wm1 = (const float*)d_in[19];
  const float* gm1 = (const float*)d_in[20];
  const float* bm1 = (const float*)d_in[21];
  const float* mm1 = (const float*)d_in[22];
  const float* vm1 = (const float*)d_in[23];
  const float* Wm2 = (const float*)d_in[24];
  const float* gm2 = (const float*)d_in[25];
  const float* bm2 = (const float*)d_in[26];
  const float* mm2 = (const float*)d_in[27];
  const float* vm2 = (const float*)d_in[28];
  const float* Wm3 = (const float*)d_in[29];
  float* out = (float*)d_out;

  char* base = (char*)d_ws;
  size_t off = 0;
  auto carve = [&](size_t bytes) {
    char* p = base + off;
    off = (off + bytes + 511) & ~(size_t)511;
    return p;
  };
  unsigned short* W1b = (unsigned short*)carve(65536 * 2);
  unsigned short* W2b = (unsigned short*)carve(65536 * 2);
  unsigned short* W3b = (unsigned short*)carve(131072 * 2);
  unsigned short* Wob = (unsigned short*)carve(24576 * 2);
  float* st1 = (float*)carve(512 * 4);
  float* st2 = (float*)carve(512 * 4);
  float* st3 = (float*)carve(1024 * 4);
  float* voted_t = (float*)carve((size_t)Bb * KO * Nn * 4);    // 25.2 MB
  float* block_part = (float*)carve((size_t)2048 * KO * 4);    // 393 KB
  float* wsum = (float*)carve(Bb * KK * 4);
  float* part = (float*)carve((size_t)512 * 4 * 4096 * 4);     // 33.5 MB
  (void)ws_size; (void)n_in; (void)in_sizes; (void)out_size;

  prep_k<<<1120, 256, 0, stream>>>(W1, W2, W3, Wo, g1, b1, m1, v1, g2, b2, m2, v2,
                                   g3, b3, m3, v3, W1b, W2b, W3b, Wob, st1, st2, st3,
                                   wsum);
  backbone_k<<<2048, 256, 0, stream>>>(ff, xyz, W1b, W2b, W3b, Wob, st1, st2, st3,
                                       bo, voted_t, block_part);
  distpool_k<<<512, 256, 0, stream>>>(block_part, voted_t, ff, out, wsum, part);
  mlp_k<<<128, 256, 0, stream>>>(part, wsum, Wm1, gm1, bm1, mm1, vm1,
                                 Wm2, gm2, bm2, mm2, vm2, Wm3, out);
}

// Round 8
// 372.133 us; speedup vs baseline: 1.0711x; 1.0711x over previous
//
#include <hip/hip_runtime.h>

// Problem constants
static constexpr int Bb = 8, Nn = 16384, Cc = 256, KO = 48, KK = 16;
#define EPSBN 1e-5f

typedef short bf16x8 __attribute__((ext_vector_type(8)));
typedef float f32x4 __attribute__((ext_vector_type(4)));
typedef unsigned short u16x4 __attribute__((ext_vector_type(4)));

__device__ __forceinline__ unsigned short f2bf(float f) {
  unsigned u = __builtin_bit_cast(unsigned, f);
  u += 0x7FFFu + ((u >> 16) & 1u);   // round-to-nearest-even
  return (unsigned short)(u >> 16);
}

// Blocked LDS layout, 64-pt x 256-ch bf16 tile:
// element (p, c) at ushort index (c/8)*512 + p*8 + (c%8).
#define LADDR(p, c) ((((c) >> 3) << 9) + ((p) << 3) + ((c) & 7))

// ---------------------------------------------------------------------------
// prep: weights fp32 -> bf16 fragment-major swizzle; BN scale/shift; wsum=0;
// NEW: fp32 transposes of Wm1/Wm2/Wm3 (mlp reads columns coalesced).
// ---------------------------------------------------------------------------
__global__ void prep_k(const float* __restrict__ W1, const float* __restrict__ W2,
                       const float* __restrict__ W3, const float* __restrict__ Wo,
                       const float* __restrict__ Wm1, const float* __restrict__ Wm2,
                       const float* __restrict__ Wm3,
                       const float* __restrict__ g1, const float* __restrict__ bb1,
                       const float* __restrict__ m1, const float* __restrict__ v1,
                       const float* __restrict__ g2, const float* __restrict__ bb2,
                       const float* __restrict__ m2, const float* __restrict__ v2,
                       const float* __restrict__ g3, const float* __restrict__ bb3,
                       const float* __restrict__ m3, const float* __restrict__ v3,
                       unsigned short* __restrict__ W1b, unsigned short* __restrict__ W2b,
                       unsigned short* __restrict__ W3b, unsigned short* __restrict__ Wob,
                       float* __restrict__ WT1, float* __restrict__ WT2,
                       float* __restrict__ WT3,
                       float* __restrict__ st1, float* __restrict__ st2,
                       float* __restrict__ st3, float* __restrict__ wsum) {
  int gid = blockIdx.x * 256 + threadIdx.x;
  if (gid < 65536) {
    int r = gid >> 8, k = gid & 255;
    int dst = (((r >> 4) * 8 + (k >> 5)) << 9) + (((r & 15) | (((k >> 3) & 3) << 4)) << 3) + (k & 7);
    W1b[dst] = f2bf(W1[gid]);
  } else if (gid < 131072) {
    int g = gid - 65536;
    int r = g >> 8, k = g & 255;
    int dst = (((r >> 4) * 8 + (k >> 5)) << 9) + (((r & 15) | (((k >> 3) & 3) << 4)) << 3) + (k & 7);
    W2b[dst] = f2bf(W2[g]);
  } else if (gid < 262144) {
    int g = gid - 131072;
    int r = g >> 8, k = g & 255;           // r in [0,512)
    int h = r >> 8, rr = r & 255;
    int dst = h * 65536 + ((((rr >> 4) * 8 + (k >> 5))) << 9) +
              (((rr & 15) | (((k >> 3) & 3) << 4)) << 3) + (k & 7);
    W3b[dst] = f2bf(W3[g]);
  } else if (gid < 286720) {
    int g = gid - 262144;
    int r = g >> 9, k = g & 511;           // Wo is 48 x 512
    int dst = (((r >> 4) * 16 + (k >> 5)) << 9) + (((r & 15) | (((k >> 3) & 3) << 4)) << 3) + (k & 7);
    Wob[dst] = f2bf(Wo[g]);
  } else if (gid < 352256) {
    int g = gid - 286720;
    WT1[(g & 255) * 256 + (g >> 8)] = Wm1[g];
  } else if (gid < 417792) {
    int g = gid - 352256;
    WT2[(g & 255) * 256 + (g >> 8)] = Wm2[g];
  } else if (gid < 483328) {
    int g = gid - 417792;
    WT3[(g & 255) * 256 + (g >> 8)] = Wm3[g];
  }
  if (gid < 256) {
    float s = g1[gid] * rsqrtf(v1[gid] + EPSBN);
    st1[2 * gid] = s; st1[2 * gid + 1] = bb1[gid] - m1[gid] * s;
  } else if (gid < 512) {
    int i = gid - 256;
    float s = g2[i] * rsqrtf(v2[i] + EPSBN);
    st2[2 * i] = s; st2[2 * i + 1] = bb2[i] - m2[i] * s;
  } else if (gid < 1024) {
    int i = gid - 512;
    float s = g3[i] * rsqrtf(v3[i] + EPSBN);
    st3[2 * i] = s; st3[2 * i + 1] = bb3[i] - m3[i] * s;
  } else if (gid < 1024 + Bb * KK) {
    wsum[gid - 1024] = 0.f;
  }
}

// ---------------------------------------------------------------------------
// backbone: UNCHANGED round-6 winner (256 thr, 64 pts, 2/CU, pinned pipeline).
// ---------------------------------------------------------------------------
__device__ __forceinline__ void gemm64(const unsigned short* __restrict__ src,
                                       unsigned short* __restrict__ dst,
                                       const unsigned short* __restrict__ Wsw,
                                       const float* __restrict__ st, int tid) {
  const int lane = tid & 63;
  const int cg = tid >> 6;
  const int ln15 = lane & 15;
  const int q = lane >> 4;
  f32x4 acc[4][4] = {};
  const unsigned short* wb = Wsw + ((cg * 32) << 9) + lane * 8;

  bf16x8 A[2][8], Bf[2][8];
#pragma unroll
  for (int ct = 0; ct < 4; ++ct)
#pragma unroll
    for (int k2 = 0; k2 < 2; ++k2)
      A[0][ct * 2 + k2] = *reinterpret_cast<const bf16x8*>(wb + ((ct * 8 + k2) << 9));
#pragma unroll
  for (int pt = 0; pt < 4; ++pt)
#pragma unroll
    for (int k2 = 0; k2 < 2; ++k2)
      Bf[0][pt * 2 + k2] = *reinterpret_cast<const bf16x8*>(
          &src[((k2 * 4 + q) << 9) + ((pt * 16 + ln15) << 3)]);

#pragma unroll
  for (int h = 0; h < 4; ++h) {
    const int cur = h & 1, nxt = cur ^ 1;
    if (h < 3) {
      const int kb0 = (h + 1) * 2;
#pragma unroll
      for (int ct = 0; ct < 4; ++ct)
#pragma unroll
        for (int k2 = 0; k2 < 2; ++k2)
          A[nxt][ct * 2 + k2] = *reinterpret_cast<const bf16x8*>(wb + ((ct * 8 + kb0 + k2) << 9));
#pragma unroll
      for (int pt = 0; pt < 4; ++pt)
#pragma unroll
        for (int k2 = 0; k2 < 2; ++k2)
          Bf[nxt][pt * 2 + k2] = *reinterpret_cast<const bf16x8*>(
              &src[(((kb0 + k2) * 4 + q) << 9) + ((pt * 16 + ln15) << 3)]);
    }
    __builtin_amdgcn_sched_barrier(0);   // loads above may not sink below
#pragma unroll
    for (int k2 = 0; k2 < 2; ++k2)
#pragma unroll
      for (int ct = 0; ct < 4; ++ct)
#pragma unroll
        for (int pt = 0; pt < 4; ++pt)
          acc[ct][pt] = __builtin_amdgcn_mfma_f32_16x16x32_bf16(
              A[cur][ct * 2 + k2], Bf[cur][pt * 2 + k2], acc[ct][pt], 0, 0, 0);
  }

#pragma unroll
  for (int ct = 0; ct < 4; ++ct) {
    const int chl = cg * 64 + ct * 16 + q * 4;
    float s0[4], t0[4];
#pragma unroll
    for (int r = 0; r < 4; ++r) {
      s0[r] = st[2 * (chl + r)];
      t0[r] = st[2 * (chl + r) + 1];
    }
#pragma unroll
    for (int pt = 0; pt < 4; ++pt) {
      const int p = pt * 16 + ln15;
      u16x4 hv;
#pragma unroll
      for (int r = 0; r < 4; ++r) {
        float v = fmaxf(acc[ct][pt][r] * s0[r] + t0[r], 0.f);
        hv[r] = f2bf(v);
      }
      *reinterpret_cast<u16x4*>(&dst[LADDR(p, chl)]) = hv;
    }
  }
}

__device__ __forceinline__ void wo64(const unsigned short* __restrict__ src,
                                     const unsigned short* __restrict__ Wosw,
                                     int h, f32x4* accO, int tid) {
  const int lane = tid & 63;
  const int wave = tid >> 6;
  const int ln15 = lane & 15;
  const int q = lane >> 4;
#pragma unroll
  for (int kb = 0; kb < 8; ++kb) {
    bf16x8 bfr = *reinterpret_cast<const bf16x8*>(
        &src[((kb * 4 + q) << 9) + ((wave * 16 + ln15) << 3)]);
#pragma unroll
    for (int ot = 0; ot < 3; ++ot) {
      bf16x8 afr = *reinterpret_cast<const bf16x8*>(&Wosw[((ot * 16 + 8 * h + kb) << 9) + lane * 8]);
      accO[ot] = __builtin_amdgcn_mfma_f32_16x16x32_bf16(afr, bfr, accO[ot], 0, 0, 0);
    }
  }
}

__global__ __launch_bounds__(256, 2) void backbone_k(
    const float* __restrict__ ff, const float* __restrict__ xyz,
    const unsigned short* __restrict__ W1b, const unsigned short* __restrict__ W2b,
    const unsigned short* __restrict__ W3b, const unsigned short* __restrict__ Wob,
    const float* __restrict__ st1, const float* __restrict__ st2,
    const float* __restrict__ st3, const float* __restrict__ bo,
    float* __restrict__ voted_t, float* __restrict__ block_part) {
  __shared__ unsigned short bufA[64 * 256];   // 32 KB
  __shared__ unsigned short bufB[64 * 256];   // 32 KB
  __shared__ float sh_part[4][KO];
  const int tid = threadIdx.x;
  const int b = blockIdx.x >> 8;
  const int n0 = (blockIdx.x & 255) * 64;
  const int lane = tid & 63;
  const int wave = tid >> 6;

  {
    const float* src = ff + (size_t)(b * Nn + n0) * Cc;
#pragma unroll
    for (int i = 0; i < 16; ++i) {
      int p = (tid & 15) + 16 * (i & 3);
      int c4 = (tid >> 4) + 16 * (i >> 2);
      const float4 v = *reinterpret_cast<const float4*>(src + p * Cc + c4 * 4);
      u16x4 h;
      h.x = f2bf(v.x); h.y = f2bf(v.y); h.z = f2bf(v.z); h.w = f2bf(v.w);
      *reinterpret_cast<u16x4*>(&bufA[LADDR(p, c4 * 4)]) = h;
    }
  }
  __syncthreads();

  gemm64(bufA, bufB, W1b, st1, tid);
  __syncthreads();
  gemm64(bufB, bufA, W2b, st2, tid);
  __syncthreads();
  gemm64(bufA, bufB, W3b, st3, tid);
  __syncthreads();

  f32x4 accO[3] = {};
  wo64(bufB, Wob, 0, accO, tid);
  __syncthreads();
  gemm64(bufA, bufB, W3b + 65536, st3 + 512, tid);
  __syncthreads();
  wo64(bufB, Wob, 1, accO, tid);

  const int ln15 = lane & 15;
  const int q = lane >> 4;
  const int p = wave * 16 + ln15;
  const int n = n0 + p;
  const float* xp = xyz + (size_t)(b * Nn + n) * 3;
  float xv[3] = {xp[0], xp[1], xp[2]};
#pragma unroll
  for (int ot = 0; ot < 3; ++ot) {
#pragma unroll
    for (int r = 0; r < 4; ++r) {
      int o = ot * 16 + q * 4 + r;  // o = k*3 + d
      float v = accO[ot][r] + bo[o] + xv[o % 3];
      voted_t[(((size_t)b * KO + o) << 14) + n] = v;
      float s = v;
      s += __shfl_xor(s, 1, 64);
      s += __shfl_xor(s, 2, 64);
      s += __shfl_xor(s, 4, 64);
      s += __shfl_xor(s, 8, 64);
      if (ln15 == 0) sh_part[wave][o] = s;
    }
  }
  __syncthreads();
  if (tid < KO) {
    float t = sh_part[0][tid] + sh_part[1][tid] + sh_part[2][tid] + sh_part[3][tid];
    block_part[blockIdx.x * KO + tid] = t;
  }
}

// ---------------------------------------------------------------------------
// distpool: kp-finalize + exp(-dist) + unnormalized pooling, emitting ONE
// block-level partial (16x256) via cross-wave LDS tree (part: 8.4 MB total).
// ---------------------------------------------------------------------------
__global__ __launch_bounds__(256, 2) void distpool_k(
    const float* __restrict__ block_part, const float* __restrict__ voted_t,
    const float* __restrict__ ff, float* __restrict__ out,
    float* __restrict__ wsum, float* __restrict__ part) {
  __shared__ float kp[KO];
  __shared__ float sh[4][KO];
  __shared__ float red[64];
  __shared__ float wt[256 * 20];    // 20 KB
  __shared__ float buf[2][4096];    // 32 KB
  const int b = blockIdx.x >> 6;
  const int n0 = (blockIdx.x & 63) * 256;
  const int tid = threadIdx.x;

  // kp finalize (redundant per block; L2-resident reads)
  if (tid < 192) {
    int o = tid % KO, c = tid / KO;
    const float* bp = block_part + ((size_t)b * 256 + c * 64) * KO + o;
    float s = 0.f;
#pragma unroll 8
    for (int j = 0; j < 64; ++j) s += bp[j * KO];
    sh[c][o] = s;
  }
  __syncthreads();
  if (tid < KO) {
    float v = (sh[0][tid] + sh[1][tid] + sh[2][tid] + sh[3][tid]) * (1.0f / (float)Nn);
    kp[tid] = v;
    if ((blockIdx.x & 63) == 0) out[b * KO + tid] = v;
  }
  __syncthreads();

  const int n = n0 + tid;
  float e[KK];
#pragma unroll
  for (int k = 0; k < KK; ++k) {
    const float* base = voted_t + (((size_t)b * KO + 3 * k) << 14) + n;
    float dx = base[0] - kp[3 * k];
    float dy = base[1 << 14] - kp[3 * k + 1];
    float dz = base[2 << 14] - kp[3 * k + 2];
    e[k] = __expf(-sqrtf(dx * dx + dy * dy + dz * dz));
    wt[tid * 20 + k] = e[k];
  }
  const int wave = tid >> 6;
  const int lane = tid & 63;
#pragma unroll
  for (int k = 0; k < KK; ++k) {
    float s = e[k];
#pragma unroll
    for (int m = 1; m < 64; m <<= 1) s += __shfl_xor(s, m, 64);
    if (lane == 0) red[wave * KK + k] = s;
  }
  __syncthreads();
  if (tid < KK) {
    float s = red[tid] + red[KK + tid] + red[2 * KK + tid] + red[3 * KK + tid];
    atomicAdd(&wsum[b * KK + tid], s);
  }

  // unnormalized pooling: wave owns 64 pts, lane owns 4 channels
  const float* fp = ff + (size_t)(b * Nn + n0 + wave * 64) * Cc + lane * 4;
  f32x4 acc[KK] = {};
  for (int p = 0; p < 64; ++p) {
    f32x4 f = *reinterpret_cast<const f32x4*>(fp + (size_t)p * Cc);
    const float* wr = &wt[(wave * 64 + p) * 20];
    f32x4 w0 = *reinterpret_cast<const f32x4*>(wr);
    f32x4 w1 = *reinterpret_cast<const f32x4*>(wr + 4);
    f32x4 w2 = *reinterpret_cast<const f32x4*>(wr + 8);
    f32x4 w3 = *reinterpret_cast<const f32x4*>(wr + 12);
#pragma unroll
    for (int j = 0; j < 4; ++j) {
      acc[0 + j] += f * w0[j];
      acc[4 + j] += f * w1[j];
      acc[8 + j] += f * w2[j];
      acc[12 + j] += f * w3[j];
    }
  }
  // cross-wave tree reduce: waves 0,1 write; waves 2,3 add; then combine.
  if (wave < 2) {
#pragma unroll
    for (int k = 0; k < KK; ++k)
      *reinterpret_cast<f32x4*>(&buf[wave][(k << 8) + lane * 4]) = acc[k];
  }
  __syncthreads();
  if (wave >= 2) {
#pragma unroll
    for (int k = 0; k < KK; ++k) {
      f32x4* p = reinterpret_cast<f32x4*>(&buf[wave - 2][(k << 8) + lane * 4]);
      *p += acc[k];
    }
  }
  __syncthreads();
  float* dst = part + (size_t)blockIdx.x * 4096;
#pragma unroll
  for (int i = 0; i < 16; ++i) {
    int idx = i * 256 + tid;
    dst[idx] = buf[0][idx] + buf[1][idx];
  }
}

// ---------------------------------------------------------------------------
// kpfeat: reduce 64 block partials per (b,k), normalize by wsum.
// ---------------------------------------------------------------------------
__global__ __launch_bounds__(256) void kpfeat_k(const float* __restrict__ part,
                                                const float* __restrict__ wsum,
                                                float* __restrict__ kp_feat) {
  const int bk = blockIdx.x;          // b*16 + k
  const int b = bk >> 4;
  const int k = bk & 15;
  const int c = threadIdx.x;
  const float* pp = part + ((size_t)b * 64) * 4096 + (k << 8) + c;
  float s = 0.f;
#pragma unroll 8
  for (int i = 0; i < 64; ++i) s += pp[(size_t)i * 4096];
  kp_feat[bk * 256 + c] = s / wsum[bk];
}

// ---------------------------------------------------------------------------
// keypoint MLP: one block per (b,k); transposed weights -> every load is
// coalesced (column read). fp32 throughout.
// ---------------------------------------------------------------------------
__global__ __launch_bounds__(256) void mlp_k(
    const float* __restrict__ kp_feat,
    const float* __restrict__ WT1, const float* __restrict__ gm1,
    const float* __restrict__ bm1, const float* __restrict__ mm1,
    const float* __restrict__ vm1,
    const float* __restrict__ WT2, const float* __restrict__ gm2,
    const float* __restrict__ bm2, const float* __restrict__ mm2,
    const float* __restrict__ vm2,
    const float* __restrict__ WT3, float* __restrict__ out) {
  __shared__ float xa[256];
  __shared__ float xb[256];
  const int bk = blockIdx.x;
  const int d = threadIdx.x;
  xa[d] = kp_feat[bk * 256 + d];
  __syncthreads();
  float acc = 0.f;
  {
    const float* w = WT1 + d;
    const float4* x4 = reinterpret_cast<const float4*>(xa);
#pragma unroll 8
    for (int c4 = 0; c4 < 64; ++c4) {
      float4 x = x4[c4];
      acc += w[(4 * c4 + 0) * 256] * x.x + w[(4 * c4 + 1) * 256] * x.y +
             w[(4 * c4 + 2) * 256] * x.z + w[(4 * c4 + 3) * 256] * x.w;
    }
  }
  {
    float s = gm1[d] * rsqrtf(vm1[d] + EPSBN);
    xb[d] = fmaxf(acc * s + (bm1[d] - mm1[d] * s), 0.f);
  }
  __syncthreads();
  acc = 0.f;
  {
    const float* w = WT2 + d;
    const float4* x4 = reinterpret_cast<const float4*>(xb);
#pragma unroll 8
    for (int c4 = 0; c4 < 64; ++c4) {
      float4 x = x4[c4];
      acc += w[(4 * c4 + 0) * 256] * x.x + w[(4 * c4 + 1) * 256] * x.y +
             w[(4 * c4 + 2) * 256] * x.z + w[(4 * c4 + 3) * 256] * x.w;
    }
  }
  {
    float s = gm2[d] * rsqrtf(vm2[d] + EPSBN);
    xa[d] = fmaxf(acc * s + (bm2[d] - mm2[d] * s), 0.f);
  }
  __syncthreads();
  acc = 0.f;
  {
    const float* w = WT3 + d;
    const float4* x4 = reinterpret_cast<const float4*>(xa);
#pragma unroll 8
    for (int c4 = 0; c4 < 64; ++c4) {
      float4 x = x4[c4];
      acc += w[(4 * c4 + 0) * 256] * x.x + w[(4 * c4 + 1) * 256] * x.y +
             w[(4 * c4 + 2) * 256] * x.z + w[(4 * c4 + 3) * 256] * x.w;
    }
  }
  out[384 + bk * 256 + d] = acc;
}

// ---------------------------------------------------------------------------
// launch (5 dispatches)
// ---------------------------------------------------------------------------
extern "C" void kernel_launch(void* const* d_in, const int* in_sizes, int n_in,
                              void* d_out, int out_size, void* d_ws, size_t ws_size,
                              hipStream_t stream) {
  const float* ff  = (const float*)d_in[0];
  const float* xyz = (const float*)d_in[1];
  const float* W1 = (const float*)d_in[2];
  const float* g1 = (const float*)d_in[3];
  const float* b1 = (const float*)d_in[4];
  const float* m1 = (const float*)d_in[5];
  const float* v1 = (const float*)d_in[6];
  const float* W2 = (const float*)d_in[7];
  const float* g2 = (const float*)d_in[8];
  const float* b2 = (const float*)d_in[9];
  const float* m2 = (const float*)d_in[10];
  const float* v2 = (const float*)d_in[11];
  const float* W3 = (const float*)d_in[12];
  const float* g3 = (const float*)d_in[13];
  const float* b3 = (const float*)d_in[14];
  const float* m3 = (const float*)d_in[15];
  const float* v3 = (const float*)d_in[16];
  const float* Wo = (const float*)d_in[17];
  const float* bo = (const float*)d_in[18];
  const float* Wm1 = (const float*)d_in[19];
  const float* gm1 = (const float*)d_in[20];
  const float* bm1 = (const float*)d_in[21];
  const float* mm1 = (const float*)d_in[22];
  const float* vm1 = (const float*)d_in[23];
  const float* Wm2 = (const float*)d_in[24];
  const float* gm2 = (const float*)d_in[25];
  const float* bm2 = (const float*)d_in[26];
  const float* mm2 = (const float*)d_in[27];
  const float* vm2 = (const float*)d_in[28];
  const float* Wm3 = (const float*)d_in[29];
  float* out = (float*)d_out;

  char* base = (char*)d_ws;
  size_t off = 0;
  auto carve = [&](size_t bytes) {
    char* p = base + off;
    off = (off + bytes + 511) & ~(size_t)511;
    return p;
  };
  unsigned short* W1b = (unsigned short*)carve(65536 * 2);
  unsigned short* W2b = (unsigned short*)carve(65536 * 2);
  unsigned short* W3b = (unsigned short*)carve(131072 * 2);
  unsigned short* Wob = (unsigned short*)carve(24576 * 2);
  float* WT1 = (float*)carve(65536 * 4);
  float* WT2 = (float*)carve(65536 * 4);
  float* WT3 = (float*)carve(65536 * 4);
  float* st1 = (float*)carve(512 * 4);
  float* st2 = (float*)carve(512 * 4);
  float* st3 = (float*)carve(1024 * 4);
  float* voted_t = (float*)carve((size_t)Bb * KO * Nn * 4);    // 25.2 MB
  float* block_part = (float*)carve((size_t)2048 * KO * 4);    // 393 KB
  float* wsum = (float*)carve(Bb * KK * 4);
  float* part = (float*)carve((size_t)512 * 4096 * 4);         // 8.4 MB
  float* kp_feat = (float*)carve((size_t)Bb * KK * Cc * 4);    // 131 KB
  (void)ws_size; (void)n_in; (void)in_sizes; (void)out_size;

  prep_k<<<1888, 256, 0, stream>>>(W1, W2, W3, Wo, Wm1, Wm2, Wm3,
                                   g1, b1, m1, v1, g2, b2, m2, v2,
                                   g3, b3, m3, v3, W1b, W2b, W3b, Wob,
                                   WT1, WT2, WT3, st1, st2, st3, wsum);
  backbone_k<<<2048, 256, 0, stream>>>(ff, xyz, W1b, W2b, W3b, Wob, st1, st2, st3,
                                       bo, voted_t, block_part);
  distpool_k<<<512, 256, 0, stream>>>(block_part, voted_t, ff, out, wsum, part);
  kpfeat_k<<<Bb * KK, 256, 0, stream>>>(part, wsum, kp_feat);
  mlp_k<<<Bb * KK, 256, 0, stream>>>(kp_feat, WT1, gm1, bm1, mm1, vm1,
                                     WT2, gm2, bm2, mm2, vm2, WT3, out);
}

// Round 9
// 362.346 us; speedup vs baseline: 1.1000x; 1.0270x over previous
//
#include <hip/hip_runtime.h>

// Problem constants
static constexpr int Bb = 8, Nn = 16384, Cc = 256, KO = 48, KK = 16;
#define EPSBN 1e-5f

typedef short bf16x8 __attribute__((ext_vector_type(8)));
typedef float f32x4 __attribute__((ext_vector_type(4)));
typedef unsigned short u16x4 __attribute__((ext_vector_type(4)));

__device__ __forceinline__ unsigned short f2bf(float f) {
  unsigned u = __builtin_bit_cast(unsigned, f);
  u += 0x7FFFu + ((u >> 16) & 1u);   // round-to-nearest-even
  return (unsigned short)(u >> 16);
}

// Blocked LDS layout, 64-pt x 256-ch bf16 tile:
// element (p, c) at ushort index (c/8)*512 + p*8 + (c%8).
#define LADDR(p, c) ((((c) >> 3) << 9) + ((p) << 3) + ((c) & 7))

// ---------------------------------------------------------------------------
// prep: weights fp32 -> bf16 fragment-major swizzle; BN scale/shift; wsum=0;
// blocks >= 1120: LDS 64x64 tile transposes of Wm1/Wm2/Wm3 (coalesced R+W).
// ---------------------------------------------------------------------------
__global__ void prep_k(const float* __restrict__ W1, const float* __restrict__ W2,
                       const float* __restrict__ W3, const float* __restrict__ Wo,
                       const float* __restrict__ Wm1, const float* __restrict__ Wm2,
                       const float* __restrict__ Wm3,
                       const float* __restrict__ g1, const float* __restrict__ bb1,
                       const float* __restrict__ m1, const float* __restrict__ v1,
                       const float* __restrict__ g2, const float* __restrict__ bb2,
                       const float* __restrict__ m2, const float* __restrict__ v2,
                       const float* __restrict__ g3, const float* __restrict__ bb3,
                       const float* __restrict__ m3, const float* __restrict__ v3,
                       unsigned short* __restrict__ W1b, unsigned short* __restrict__ W2b,
                       unsigned short* __restrict__ W3b, unsigned short* __restrict__ Wob,
                       float* __restrict__ WT1, float* __restrict__ WT2,
                       float* __restrict__ WT3,
                       float* __restrict__ st1, float* __restrict__ st2,
                       float* __restrict__ st3, float* __restrict__ wsum) {
  __shared__ float tl[64 * 65];
  if (blockIdx.x >= 1120) {
    // transpose blocks: 16 tiles per matrix, 3 matrices
    const int t = blockIdx.x - 1120;
    const int mat = t >> 4;
    const int tile = t & 15;
    const int tr = tile >> 2, tc = tile & 3;
    const float* Wm = (mat == 0) ? Wm1 : (mat == 1) ? Wm2 : Wm3;
    float* WT = (mat == 0) ? WT1 : (mat == 1) ? WT2 : WT3;
    const int tid = threadIdx.x;
    const int lr = tid >> 6;        // 0..3
    const int lc = tid & 63;
#pragma unroll
    for (int i = 0; i < 16; ++i) {
      int sr = i * 4 + lr;
      tl[sr * 65 + lc] = Wm[(tr * 64 + sr) * 256 + tc * 64 + lc];
    }
    __syncthreads();
#pragma unroll
    for (int i = 0; i < 16; ++i) {
      int sc = i * 4 + lr;          // output row = source col
      WT[(tc * 64 + sc) * 256 + tr * 64 + lc] = tl[lc * 65 + sc];
    }
    return;
  }
  int gid = blockIdx.x * 256 + threadIdx.x;
  if (gid < 65536) {
    int r = gid >> 8, k = gid & 255;
    int dst = (((r >> 4) * 8 + (k >> 5)) << 9) + (((r & 15) | (((k >> 3) & 3) << 4)) << 3) + (k & 7);
    W1b[dst] = f2bf(W1[gid]);
  } else if (gid < 131072) {
    int g = gid - 65536;
    int r = g >> 8, k = g & 255;
    int dst = (((r >> 4) * 8 + (k >> 5)) << 9) + (((r & 15) | (((k >> 3) & 3) << 4)) << 3) + (k & 7);
    W2b[dst] = f2bf(W2[g]);
  } else if (gid < 262144) {
    int g = gid - 131072;
    int r = g >> 8, k = g & 255;           // r in [0,512)
    int h = r >> 8, rr = r & 255;
    int dst = h * 65536 + ((((rr >> 4) * 8 + (k >> 5))) << 9) +
              (((rr & 15) | (((k >> 3) & 3) << 4)) << 3) + (k & 7);
    W3b[dst] = f2bf(W3[g]);
  } else if (gid < 286720) {
    int g = gid - 262144;
    int r = g >> 9, k = g & 511;           // Wo is 48 x 512
    int dst = (((r >> 4) * 16 + (k >> 5)) << 9) + (((r & 15) | (((k >> 3) & 3) << 4)) << 3) + (k & 7);
    Wob[dst] = f2bf(Wo[g]);
  }
  if (gid < 256) {
    float s = g1[gid] * rsqrtf(v1[gid] + EPSBN);
    st1[2 * gid] = s; st1[2 * gid + 1] = bb1[gid] - m1[gid] * s;
  } else if (gid < 512) {
    int i = gid - 256;
    float s = g2[i] * rsqrtf(v2[i] + EPSBN);
    st2[2 * i] = s; st2[2 * i + 1] = bb2[i] - m2[i] * s;
  } else if (gid < 1024) {
    int i = gid - 512;
    float s = g3[i] * rsqrtf(v3[i] + EPSBN);
    st3[2 * i] = s; st3[2 * i + 1] = bb3[i] - m3[i] * s;
  } else if (gid < 1024 + Bb * KK) {
    wsum[gid - 1024] = 0.f;
  }
}

// ---------------------------------------------------------------------------
// backbone: UNCHANGED round-6 winner (256 thr, 64 pts, 2/CU, pinned pipeline).
// ---------------------------------------------------------------------------
__device__ __forceinline__ void gemm64(const unsigned short* __restrict__ src,
                                       unsigned short* __restrict__ dst,
                                       const unsigned short* __restrict__ Wsw,
                                       const float* __restrict__ st, int tid) {
  const int lane = tid & 63;
  const int cg = tid >> 6;
  const int ln15 = lane & 15;
  const int q = lane >> 4;
  f32x4 acc[4][4] = {};
  const unsigned short* wb = Wsw + ((cg * 32) << 9) + lane * 8;

  bf16x8 A[2][8], Bf[2][8];
#pragma unroll
  for (int ct = 0; ct < 4; ++ct)
#pragma unroll
    for (int k2 = 0; k2 < 2; ++k2)
      A[0][ct * 2 + k2] = *reinterpret_cast<const bf16x8*>(wb + ((ct * 8 + k2) << 9));
#pragma unroll
  for (int pt = 0; pt < 4; ++pt)
#pragma unroll
    for (int k2 = 0; k2 < 2; ++k2)
      Bf[0][pt * 2 + k2] = *reinterpret_cast<const bf16x8*>(
          &src[((k2 * 4 + q) << 9) + ((pt * 16 + ln15) << 3)]);

#pragma unroll
  for (int h = 0; h < 4; ++h) {
    const int cur = h & 1, nxt = cur ^ 1;
    if (h < 3) {
      const int kb0 = (h + 1) * 2;
#pragma unroll
      for (int ct = 0; ct < 4; ++ct)
#pragma unroll
        for (int k2 = 0; k2 < 2; ++k2)
          A[nxt][ct * 2 + k2] = *reinterpret_cast<const bf16x8*>(wb + ((ct * 8 + kb0 + k2) << 9));
#pragma unroll
      for (int pt = 0; pt < 4; ++pt)
#pragma unroll
        for (int k2 = 0; k2 < 2; ++k2)
          Bf[nxt][pt * 2 + k2] = *reinterpret_cast<const bf16x8*>(
              &src[(((kb0 + k2) * 4 + q) << 9) + ((pt * 16 + ln15) << 3)]);
    }
    __builtin_amdgcn_sched_barrier(0);   // loads above may not sink below
#pragma unroll
    for (int k2 = 0; k2 < 2; ++k2)
#pragma unroll
      for (int ct = 0; ct < 4; ++ct)
#pragma unroll
        for (int pt = 0; pt < 4; ++pt)
          acc[ct][pt] = __builtin_amdgcn_mfma_f32_16x16x32_bf16(
              A[cur][ct * 2 + k2], Bf[cur][pt * 2 + k2], acc[ct][pt], 0, 0, 0);
  }

#pragma unroll
  for (int ct = 0; ct < 4; ++ct) {
    const int chl = cg * 64 + ct * 16 + q * 4;
    float s0[4], t0[4];
#pragma unroll
    for (int r = 0; r < 4; ++r) {
      s0[r] = st[2 * (chl + r)];
      t0[r] = st[2 * (chl + r) + 1];
    }
#pragma unroll
    for (int pt = 0; pt < 4; ++pt) {
      const int p = pt * 16 + ln15;
      u16x4 hv;
#pragma unroll
      for (int r = 0; r < 4; ++r) {
        float v = fmaxf(acc[ct][pt][r] * s0[r] + t0[r], 0.f);
        hv[r] = f2bf(v);
      }
      *reinterpret_cast<u16x4*>(&dst[LADDR(p, chl)]) = hv;
    }
  }
}

__device__ __forceinline__ void wo64(const unsigned short* __restrict__ src,
                                     const unsigned short* __restrict__ Wosw,
                                     int h, f32x4* accO, int tid) {
  const int lane = tid & 63;
  const int wave = tid >> 6;
  const int ln15 = lane & 15;
  const int q = lane >> 4;
#pragma unroll
  for (int kb = 0; kb < 8; ++kb) {
    bf16x8 bfr = *reinterpret_cast<const bf16x8*>(
        &src[((kb * 4 + q) << 9) + ((wave * 16 + ln15) << 3)]);
#pragma unroll
    for (int ot = 0; ot < 3; ++ot) {
      bf16x8 afr = *reinterpret_cast<const bf16x8*>(&Wosw[((ot * 16 + 8 * h + kb) << 9) + lane * 8]);
      accO[ot] = __builtin_amdgcn_mfma_f32_16x16x32_bf16(afr, bfr, accO[ot], 0, 0, 0);
    }
  }
}

__global__ __launch_bounds__(256, 2) void backbone_k(
    const float* __restrict__ ff, const float* __restrict__ xyz,
    const unsigned short* __restrict__ W1b, const unsigned short* __restrict__ W2b,
    const unsigned short* __restrict__ W3b, const unsigned short* __restrict__ Wob,
    const float* __restrict__ st1, const float* __restrict__ st2,
    const float* __restrict__ st3, const float* __restrict__ bo,
    float* __restrict__ voted_t, float* __restrict__ block_part) {
  __shared__ unsigned short bufA[64 * 256];   // 32 KB
  __shared__ unsigned short bufB[64 * 256];   // 32 KB
  __shared__ float sh_part[4][KO];
  const int tid = threadIdx.x;
  const int b = blockIdx.x >> 8;
  const int n0 = (blockIdx.x & 255) * 64;
  const int lane = tid & 63;
  const int wave = tid >> 6;

  {
    const float* src = ff + (size_t)(b * Nn + n0) * Cc;
#pragma unroll
    for (int i = 0; i < 16; ++i) {
      int p = (tid & 15) + 16 * (i & 3);
      int c4 = (tid >> 4) + 16 * (i >> 2);
      const float4 v = *reinterpret_cast<const float4*>(src + p * Cc + c4 * 4);
      u16x4 h;
      h.x = f2bf(v.x); h.y = f2bf(v.y); h.z = f2bf(v.z); h.w = f2bf(v.w);
      *reinterpret_cast<u16x4*>(&bufA[LADDR(p, c4 * 4)]) = h;
    }
  }
  __syncthreads();

  gemm64(bufA, bufB, W1b, st1, tid);
  __syncthreads();
  gemm64(bufB, bufA, W2b, st2, tid);
  __syncthreads();
  gemm64(bufA, bufB, W3b, st3, tid);
  __syncthreads();

  f32x4 accO[3] = {};
  wo64(bufB, Wob, 0, accO, tid);
  __syncthreads();
  gemm64(bufA, bufB, W3b + 65536, st3 + 512, tid);
  __syncthreads();
  wo64(bufB, Wob, 1, accO, tid);

  const int ln15 = lane & 15;
  const int q = lane >> 4;
  const int p = wave * 16 + ln15;
  const int n = n0 + p;
  const float* xp = xyz + (size_t)(b * Nn + n) * 3;
  float xv[3] = {xp[0], xp[1], xp[2]};
#pragma unroll
  for (int ot = 0; ot < 3; ++ot) {
#pragma unroll
    for (int r = 0; r < 4; ++r) {
      int o = ot * 16 + q * 4 + r;  // o = k*3 + d
      float v = accO[ot][r] + bo[o] + xv[o % 3];
      voted_t[(((size_t)b * KO + o) << 14) + n] = v;
      float s = v;
      s += __shfl_xor(s, 1, 64);
      s += __shfl_xor(s, 2, 64);
      s += __shfl_xor(s, 4, 64);
      s += __shfl_xor(s, 8, 64);
      if (ln15 == 0) sh_part[wave][o] = s;
    }
  }
  __syncthreads();
  if (tid < KO) {
    float t = sh_part[0][tid] + sh_part[1][tid] + sh_part[2][tid] + sh_part[3][tid];
    block_part[blockIdx.x * KO + tid] = t;
  }
}

// ---------------------------------------------------------------------------
// distpool: kp-finalize + exp(-dist) + unnormalized pooling (block partial).
// Pooling loop unrolled x4: 4 independent ff loads in flight per iteration
// (~32 KB/CU outstanding -> stream HBM instead of latency-chaining).
// ---------------------------------------------------------------------------
__global__ __launch_bounds__(256, 2) void distpool_k(
    const float* __restrict__ block_part, const float* __restrict__ voted_t,
    const float* __restrict__ ff, float* __restrict__ out,
    float* __restrict__ wsum, float* __restrict__ part) {
  __shared__ float kp[KO];
  __shared__ float sh[4][KO];
  __shared__ float red[64];
  __shared__ float wt[256 * 20];    // 20 KB
  __shared__ float buf[2][4096];    // 32 KB
  const int b = blockIdx.x >> 6;
  const int n0 = (blockIdx.x & 63) * 256;
  const int tid = threadIdx.x;

  // kp finalize (redundant per block; L2-resident reads)
  if (tid < 192) {
    int o = tid % KO, c = tid / KO;
    const float* bp = block_part + ((size_t)b * 256 + c * 64) * KO + o;
    float s = 0.f;
#pragma unroll 8
    for (int j = 0; j < 64; ++j) s += bp[j * KO];
    sh[c][o] = s;
  }
  __syncthreads();
  if (tid < KO) {
    float v = (sh[0][tid] + sh[1][tid] + sh[2][tid] + sh[3][tid]) * (1.0f / (float)Nn);
    kp[tid] = v;
    if ((blockIdx.x & 63) == 0) out[b * KO + tid] = v;
  }
  __syncthreads();

  const int n = n0 + tid;
  float e[KK];
#pragma unroll
  for (int k = 0; k < KK; ++k) {
    const float* base = voted_t + (((size_t)b * KO + 3 * k) << 14) + n;
    float dx = base[0] - kp[3 * k];
    float dy = base[1 << 14] - kp[3 * k + 1];
    float dz = base[2 << 14] - kp[3 * k + 2];
    e[k] = __expf(-sqrtf(dx * dx + dy * dy + dz * dz));
    wt[tid * 20 + k] = e[k];
  }
  const int wave = tid >> 6;
  const int lane = tid & 63;
#pragma unroll
  for (int k = 0; k < KK; ++k) {
    float s = e[k];
#pragma unroll
    for (int m = 1; m < 64; m <<= 1) s += __shfl_xor(s, m, 64);
    if (lane == 0) red[wave * KK + k] = s;
  }
  __syncthreads();
  if (tid < KK) {
    float s = red[tid] + red[KK + tid] + red[2 * KK + tid] + red[3 * KK + tid];
    atomicAdd(&wsum[b * KK + tid], s);
  }

  // unnormalized pooling: wave owns 64 pts, lane owns 4 channels; x4 unroll
  const float* fp = ff + (size_t)(b * Nn + n0 + wave * 64) * Cc + lane * 4;
  f32x4 acc[KK] = {};
  for (int p0 = 0; p0 < 64; p0 += 4) {
    f32x4 f[4];
#pragma unroll
    for (int j = 0; j < 4; ++j)
      f[j] = *reinterpret_cast<const f32x4*>(fp + (size_t)(p0 + j) * Cc);
#pragma unroll
    for (int j = 0; j < 4; ++j) {
      const float* wr = &wt[(wave * 64 + p0 + j) * 20];
      f32x4 w0 = *reinterpret_cast<const f32x4*>(wr);
      f32x4 w1 = *reinterpret_cast<const f32x4*>(wr + 4);
      f32x4 w2 = *reinterpret_cast<const f32x4*>(wr + 8);
      f32x4 w3 = *reinterpret_cast<const f32x4*>(wr + 12);
#pragma unroll
      for (int jj = 0; jj < 4; ++jj) {
        acc[0 + jj] += f[j] * w0[jj];
        acc[4 + jj] += f[j] * w1[jj];
        acc[8 + jj] += f[j] * w2[jj];
        acc[12 + jj] += f[j] * w3[jj];
      }
    }
  }
  // cross-wave tree reduce: waves 0,1 write; waves 2,3 add; then combine.
  if (wave < 2) {
#pragma unroll
    for (int k = 0; k < KK; ++k)
      *reinterpret_cast<f32x4*>(&buf[wave][(k << 8) + lane * 4]) = acc[k];
  }
  __syncthreads();
  if (wave >= 2) {
#pragma unroll
    for (int k = 0; k < KK; ++k) {
      f32x4* p = reinterpret_cast<f32x4*>(&buf[wave - 2][(k << 8) + lane * 4]);
      *p += acc[k];
    }
  }
  __syncthreads();
  float* dst = part + (size_t)blockIdx.x * 4096;
#pragma unroll
  for (int i = 0; i < 16; ++i) {
    int idx = i * 256 + tid;
    dst[idx] = buf[0][idx] + buf[1][idx];
  }
}

// ---------------------------------------------------------------------------
// keypoint MLP: one block per (b,k); inline partial-reduce + 1/wsum, then
// 3 fp32 layers with transposed (coalesced) weights.
// ---------------------------------------------------------------------------
__global__ __launch_bounds__(256) void mlp_k(
    const float* __restrict__ part, const float* __restrict__ wsum,
    const float* __restrict__ WT1, const float* __restrict__ gm1,
    const float* __restrict__ bm1, const float* __restrict__ mm1,
    const float* __restrict__ vm1,
    const float* __restrict__ WT2, const float* __restrict__ gm2,
    const float* __restrict__ bm2, const float* __restrict__ mm2,
    const float* __restrict__ vm2,
    const float* __restrict__ WT3, float* __restrict__ out) {
  __shared__ float xa[256];
  __shared__ float xb[256];
  const int bk = blockIdx.x;
  const int b = bk >> 4;
  const int k = bk & 15;
  const int d = threadIdx.x;
  {
    const float* pp = part + ((size_t)b * 64) * 4096 + (k << 8) + d;
    float s = 0.f;
#pragma unroll 8
    for (int i = 0; i < 64; ++i) s += pp[(size_t)i * 4096];
    xa[d] = s / wsum[bk];
  }
  __syncthreads();
  float acc = 0.f;
  {
    const float* w = WT1 + d;
    const float4* x4 = reinterpret_cast<const float4*>(xa);
#pragma unroll 8
    for (int c4 = 0; c4 < 64; ++c4) {
      float4 x = x4[c4];
      acc += w[(4 * c4 + 0) * 256] * x.x + w[(4 * c4 + 1) * 256] * x.y +
             w[(4 * c4 + 2) * 256] * x.z + w[(4 * c4 + 3) * 256] * x.w;
    }
  }
  {
    float s = gm1[d] * rsqrtf(vm1[d] + EPSBN);
    xb[d] = fmaxf(acc * s + (bm1[d] - mm1[d] * s), 0.f);
  }
  __syncthreads();
  acc = 0.f;
  {
    const float* w = WT2 + d;
    const float4* x4 = reinterpret_cast<const float4*>(xb);
#pragma unroll 8
    for (int c4 = 0; c4 < 64; ++c4) {
      float4 x = x4[c4];
      acc += w[(4 * c4 + 0) * 256] * x.x + w[(4 * c4 + 1) * 256] * x.y +
             w[(4 * c4 + 2) * 256] * x.z + w[(4 * c4 + 3) * 256] * x.w;
    }
  }
  {
    float s = gm2[d] * rsqrtf(vm2[d] + EPSBN);
    xa[d] = fmaxf(acc * s + (bm2[d] - mm2[d] * s), 0.f);
  }
  __syncthreads();
  acc = 0.f;
  {
    const float* w = WT3 + d;
    const float4* x4 = reinterpret_cast<const float4*>(xa);
#pragma unroll 8
    for (int c4 = 0; c4 < 64; ++c4) {
      float4 x = x4[c4];
      acc += w[(4 * c4 + 0) * 256] * x.x + w[(4 * c4 + 1) * 256] * x.y +
             w[(4 * c4 + 2) * 256] * x.z + w[(4 * c4 + 3) * 256] * x.w;
    }
  }
  out[384 + bk * 256 + d] = acc;
}

// ---------------------------------------------------------------------------
// launch (4 dispatches)
// ---------------------------------------------------------------------------
extern "C" void kernel_launch(void* const* d_in, const int* in_sizes, int n_in,
                              void* d_out, int out_size, void* d_ws, size_t ws_size,
                              hipStream_t stream) {
  const float* ff  = (const float*)d_in[0];
  const float* xyz = (const float*)d_in[1];
  const float* W1 = (const float*)d_in[2];
  const float* g1 = (const float*)d_in[3];
  const float* b1 = (const float*)d_in[4];
  const float* m1 = (const float*)d_in[5];
  const float* v1 = (const float*)d_in[6];
  const float* W2 = (const float*)d_in[7];
  const float* g2 = (const float*)d_in[8];
  const float* b2 = (const float*)d_in[9];
  const float* m2 = (const float*)d_in[10];
  const float* v2 = (const float*)d_in[11];
  const float* W3 = (const float*)d_in[12];
  const float* g3 = (const float*)d_in[13];
  const float* b3 = (const float*)d_in[14];
  const float* m3 = (const float*)d_in[15];
  const float* v3 = (const float*)d_in[16];
  const float* Wo = (const float*)d_in[17];
  const float* bo = (const float*)d_in[18];
  const float* Wm1 = (const float*)d_in[19];
  const float* gm1 = (const float*)d_in[20];
  const float* bm1 = (const float*)d_in[21];
  const float* mm1 = (const float*)d_in[22];
  const float* vm1 = (const float*)d_in[23];
  const float* Wm2 = (const float*)d_in[24];
  const float* gm2 = (const float*)d_in[25];
  const float* bm2 = (const float*)d_in[26];
  const float* mm2 = (const float*)d_in[27];
  const float* vm2 = (const float*)d_in[28];
  const float* Wm3 = (const float*)d_in[29];
  float* out = (float*)d_out;

  char* base = (char*)d_ws;
  size_t off = 0;
  auto carve = [&](size_t bytes) {
    char* p = base + off;
    off = (off + bytes + 511) & ~(size_t)511;
    return p;
  };
  unsigned short* W1b = (unsigned short*)carve(65536 * 2);
  unsigned short* W2b = (unsigned short*)carve(65536 * 2);
  unsigned short* W3b = (unsigned short*)carve(131072 * 2);
  unsigned short* Wob = (unsigned short*)carve(24576 * 2);
  float* WT1 = (float*)carve(65536 * 4);
  float* WT2 = (float*)carve(65536 * 4);
  float* WT3 = (float*)carve(65536 * 4);
  float* st1 = (float*)carve(512 * 4);
  float* st2 = (float*)carve(512 * 4);
  float* st3 = (float*)carve(1024 * 4);
  float* voted_t = (float*)carve((size_t)Bb * KO * Nn * 4);    // 25.2 MB
  float* block_part = (float*)carve((size_t)2048 * KO * 4);    // 393 KB
  float* wsum = (float*)carve(Bb * KK * 4);
  float* part = (float*)carve((size_t)512 * 4096 * 4);         // 8.4 MB
  (void)ws_size; (void)n_in; (void)in_sizes; (void)out_size;

  prep_k<<<1168, 256, 0, stream>>>(W1, W2, W3, Wo, Wm1, Wm2, Wm3,
                                   g1, b1, m1, v1, g2, b2, m2, v2,
                                   g3, b3, m3, v3, W1b, W2b, W3b, Wob,
                                   WT1, WT2, WT3, st1, st2, st3, wsum);
  backbone_k<<<2048, 256, 0, stream>>>(ff, xyz, W1b, W2b, W3b, Wob, st1, st2, st3,
                                       bo, voted_t, block_part);
  distpool_k<<<512, 256, 0, stream>>>(block_part, voted_t, ff, out, wsum, part);
  mlp_k<<<Bb * KK, 256, 0, stream>>>(part, wsum, WT1, gm1, bm1, mm1, vm1,
                                     WT2, gm2, bm2, mm2, vm2, WT3, out);
}